// Round 9
// baseline (228.913 us; speedup 1.0000x reference)
//
#include <hip/hip_runtime.h>
#include <hip/hip_bf16.h>

#define DFEAT 64
#define NBSH  8        // bucket = dst >> 8  (256 nodes per bucket)
#define NPB   256      // nodes per bucket
#define EPB   8192     // edges per partition block

// ---- A: per-block bucket histogram (LDS); blkhistT layout [bucket][block] ----
__global__ __launch_bounds__(256) void histA_kernel(const int* __restrict__ ei,
                                                    int* __restrict__ blkhistT,
                                                    int E, int nblk) {
    __shared__ int h[512];
    int t = threadIdx.x;
    h[t] = 0; h[t + 256] = 0;
    __syncthreads();
    int base = blockIdx.x * EPB;
    #pragma unroll
    for (int i = 0; i < EPB / 256; ++i) {
        int e = base + i * 256 + t;
        if (e < E) atomicAdd(&h[ei[E + e] >> NBSH], 1);
    }
    __syncthreads();
    blkhistT[t * nblk + blockIdx.x]         = h[t];
    blkhistT[(t + 256) * nblk + blockIdx.x] = h[t + 256];
}

// ---- B1: per-bucket exclusive scan over blocks (512 blocks, contiguous rows) ----
__global__ __launch_bounds__(256) void scanB1_kernel(int* __restrict__ blkhistT,
                                                     int* __restrict__ buckettotal, int nblk) {
    __shared__ int lds[256];
    int t = threadIdx.x;
    int b = blockIdx.x;
    int v = (t < nblk) ? blkhistT[b * nblk + t] : 0;
    lds[t] = v;
    __syncthreads();
    #pragma unroll
    for (int off = 1; off < 256; off <<= 1) {
        int y = (t >= off) ? lds[t - off] : 0;
        __syncthreads();
        lds[t] += y;
        __syncthreads();
    }
    if (t < nblk) blkhistT[b * nblk + t] = lds[t] - v;   // block-local base
    if (t == 255) buckettotal[b] = lds[255];
}

// ---- B2: single block, exclusive scan of 512 bucket totals ----
__global__ __launch_bounds__(512) void scanB2_kernel(const int* __restrict__ buckettotal,
                                                     int* __restrict__ bucketbase) {
    __shared__ int lds[512];
    int t = threadIdx.x;
    int s = buckettotal[t];
    lds[t] = s;
    __syncthreads();
    #pragma unroll
    for (int off = 1; off < 512; off <<= 1) {
        int y = (t >= off) ? lds[t - off] : 0;
        __syncthreads();
        lds[t] += y;
        __syncthreads();
    }
    bucketbase[t] = lds[t] - s;
    if (t == 511) bucketbase[512] = lds[511];
}

// ---- C: partition edges into buckets; pack (dst&255)<<17 | src (4B/edge) ----
__global__ __launch_bounds__(256) void partC_kernel(const int* __restrict__ ei,
                                                    const int* __restrict__ blkhistT,
                                                    const int* __restrict__ bucketbase,
                                                    unsigned* __restrict__ ebuf, int E, int nblk) {
    __shared__ int cur[512];
    int t = threadIdx.x;
    cur[t]       = bucketbase[t]       + blkhistT[t * nblk + blockIdx.x];
    cur[t + 256] = bucketbase[t + 256] + blkhistT[(t + 256) * nblk + blockIdx.x];
    __syncthreads();
    int base = blockIdx.x * EPB;
    #pragma unroll
    for (int i = 0; i < EPB / 256; ++i) {
        int e = base + i * 256 + t;
        if (e < E) {
            int s = ei[e];
            int d = ei[E + e];
            int pos = atomicAdd(&cur[d >> NBSH], 1);
            ebuf[pos] = (unsigned)s | ((unsigned)(d & (NPB - 1)) << 17);
        }
    }
}

// ---- D: per-bucket CSR build in LDS + fused dinv + bf16 xs pack ----
// Segment layout per node: [self][edges...][sentinels to pad len to x4]
__global__ __launch_bounds__(256) void csrD_kernel(const unsigned* __restrict__ ebuf,
                                                   const int* __restrict__ bucketbase,
                                                   const float* __restrict__ x,
                                                   int* __restrict__ srcs,
                                                   int* __restrict__ begs,
                                                   int* __restrict__ lens,
                                                   float* __restrict__ dinv,
                                                   unsigned* __restrict__ xs, int n) {
    __shared__ int cnt[256];
    __shared__ int tmp[256];
    __shared__ float dl[256];
    int t = threadIdx.x;
    int b = blockIdx.x;
    int ebeg = bucketbase[b], eend = bucketbase[b + 1];
    int regionbase = ebeg + b * (4 * NPB);     // +4 pad slots per node
    cnt[t] = 0;
    __syncthreads();
    for (int e = ebeg + t; e < eend; e += 256)
        atomicAdd(&cnt[ebuf[e] >> 17], 1);
    __syncthreads();
    int nid = (b << NBSH) + t;
    int deg = cnt[t];
    int slots = (nid < n) ? ((deg + 4) & ~3) : 0;
    tmp[t] = slots;
    __syncthreads();
    int s = slots;
    for (int o = 1; o < 256; o <<= 1) {
        int y = (t >= o) ? tmp[t - o] : 0;
        __syncthreads();
        tmp[t] += y;
        __syncthreads();
    }
    int excl = tmp[t] - s;
    float di = rsqrtf((float)(deg + 1));
    dl[t] = di;
    if (nid < n) {
        int beg_abs = regionbase + excl;
        begs[nid] = beg_abs;
        lens[nid] = slots;
        dinv[nid] = di;
        srcs[beg_abs] = nid;                            // self-loop slot
        for (int k = deg + 1; k < slots; ++k) srcs[beg_abs + k] = n;  // sentinels
    }
    cnt[t] = excl + 1;                                  // cursor past self slot
    __syncthreads();                                    // (also publishes dl[])
    for (int e = ebeg + t; e < eend; e += 256) {
        unsigned v = ebuf[e];
        int pos = atomicAdd(&cnt[v >> 17], 1);
        srcs[regionbase + pos] = (int)(v & 0x1ffffu);
    }
    // fused xs pack for this bucket's 256 nodes (+ zero row for node n)
    int base_nid = b << NBSH;
    for (int f = t; f < NPB * 32; f += 256) {
        int rr = f >> 5, c = f & 31;
        int node = base_nid + rr;
        if (node > n) continue;
        unsigned v = 0;
        if (node < n) {
            float dd = dl[rr];
            float f0 = x[node * DFEAT + 2 * c] * dd;
            float f1 = x[node * DFEAT + 2 * c + 1] * dd;
            unsigned u0 = __float_as_uint(f0); u0 = (u0 + 0x7fffu + ((u0 >> 16) & 1u)) >> 16;
            unsigned u1 = __float_as_uint(f1); u1 = (u1 + 0x7fffu + ((u1 >> 16) & 1u)) >> 16;
            v = (u0 & 0xffffu) | (u1 << 16);
        }
        xs[node * 32 + c] = v;    // node==n -> zero sentinel row
    }
}

// ---- Persistent fused gather (uint4: 8 rows in flight) -> GEMM(+bias) -> expmap0 -> proj
__global__ __launch_bounds__(256) void agg_kernel(const int* __restrict__ begs,
                                                  const int* __restrict__ lens,
                                                  const int* __restrict__ srcs,
                                                  const float* __restrict__ dinv,
                                                  const uint4* __restrict__ xs4,
                                                  const float* __restrict__ W,
                                                  const float* __restrict__ b,
                                                  float* __restrict__ out,
                                                  int n, int nquads) {
    __shared__ float Wl[DFEAT * DFEAT];   // 16 KB
    __shared__ float xl[4][DFEAT];
    int t = threadIdx.x;
    #pragma unroll
    for (int i = 0; i < 16; ++i) Wl[i * 256 + t] = W[i * 256 + t];
    __syncthreads();   // the ONLY barrier

    int r = t >> 6, lane = t & 63;
    int g = lane >> 3;        // edge group (0..7)
    int q = lane & 7;         // uint4 column -> features 8q..8q+7
    float bias = b[lane];

    for (int quad = blockIdx.x; quad < nquads; quad += gridDim.x) {
        int node = quad * 4 + r;
        if (node >= n) continue;

        float f0 = 0, f1 = 0, f2 = 0, f3 = 0, f4 = 0, f5 = 0, f6 = 0, f7 = 0;
        int beg = begs[node];
        int end = beg + lens[node];            // multiple of 4
        for (int base = beg; base < end; base += 64) {
            int m = end - base; if (m > 64) m = 64;   // multiple of 4
            int idx = 0;
            if (lane < m) idx = srcs[base + lane];
            int octs = m >> 3;
            for (int j = 0; j < octs; ++j) {
                int sv = __shfl(idx, 8 * j + g, 64);
                uint4 d = xs4[(unsigned)sv * 8 + q];
                f0 += __uint_as_float(d.x << 16);
                f1 += __uint_as_float(d.x & 0xffff0000u);
                f2 += __uint_as_float(d.y << 16);
                f3 += __uint_as_float(d.y & 0xffff0000u);
                f4 += __uint_as_float(d.z << 16);
                f5 += __uint_as_float(d.z & 0xffff0000u);
                f6 += __uint_as_float(d.w << 16);
                f7 += __uint_as_float(d.w & 0xffff0000u);
            }
            if (m & 4) {   // 4-edge remainder: groups 0..3 real, 4..7 masked dups
                int sv = __shfl(idx, 8 * octs + (g & 3), 64);
                uint4 d = xs4[(unsigned)sv * 8 + q];
                if (g < 4) {
                    f0 += __uint_as_float(d.x << 16);
                    f1 += __uint_as_float(d.x & 0xffff0000u);
                    f2 += __uint_as_float(d.y << 16);
                    f3 += __uint_as_float(d.y & 0xffff0000u);
                    f4 += __uint_as_float(d.z << 16);
                    f5 += __uint_as_float(d.z & 0xffff0000u);
                    f6 += __uint_as_float(d.w << 16);
                    f7 += __uint_as_float(d.w & 0xffff0000u);
                }
            }
        }
        // reduce across the 8 edge-groups (lane bits 3..5)
        #pragma unroll
        for (int off = 8; off < 64; off <<= 1) {
            f0 += __shfl_xor(f0, off, 64);
            f1 += __shfl_xor(f1, off, 64);
            f2 += __shfl_xor(f2, off, 64);
            f3 += __shfl_xor(f3, off, 64);
            f4 += __shfl_xor(f4, off, 64);
            f5 += __shfl_xor(f5, off, 64);
            f6 += __shfl_xor(f6, off, 64);
            f7 += __shfl_xor(f7, off, 64);
        }
        if (g == 0) {
            float di = dinv[node];
            xl[r][8 * q + 0] = f0 * di;
            xl[r][8 * q + 1] = f1 * di;
            xl[r][8 * q + 2] = f2 * di;
            xl[r][8 * q + 3] = f3 * di;
            xl[r][8 * q + 4] = f4 * di;
            xl[r][8 * q + 5] = f5 * di;
            xl[r][8 * q + 6] = f6 * di;
            xl[r][8 * q + 7] = f7 * di;
        }
        // wave-synchronous LDS: same wave wrote xl[r], same wave reads it.

        float o0 = bias, o1 = 0.0f;
        #pragma unroll
        for (int k = 0; k < DFEAT; k += 2) {
            o0 = fmaf(xl[r][k],     Wl[k * DFEAT + lane],       o0);
            o1 = fmaf(xl[r][k + 1], Wl[(k + 1) * DFEAT + lane], o1);
        }
        float o = o0 + o1;

        float ss = o * o;
        #pragma unroll
        for (int off = 32; off > 0; off >>= 1) ss += __shfl_xor(ss, off, 64);
        float norm = fmaxf(sqrtf(ss), 1e-15f);
        float sc = fminf(tanhf(norm), 1.0f - 4e-3f) / norm;
        out[(long long)node * DFEAT + lane] = o * sc;
    }
}

// ---------------- launch ----------------

extern "C" void kernel_launch(void* const* d_in, const int* in_sizes, int n_in,
                              void* d_out, int out_size, void* d_ws, size_t ws_size,
                              hipStream_t stream) {
    const float* x = (const float*)d_in[0];
    const float* W = (const float*)d_in[1];
    const float* b = (const float*)d_in[2];
    const int* ei  = (const int*)d_in[3];

    int n = in_sizes[0] / DFEAT;           // 100000
    int E = in_sizes[3] / 2;               // 1200000
    int NB = (n + NPB - 1) / NPB;          // 391 buckets
    int nblk = (E + EPB - 1) / EPB;        // 147 partition blocks
    int nquads = (n + 3) / 4;              // 25000

    // workspace layout (ints), ~25.5 MB total; xs kept SEPARATE from ebuf
    // (csrD writes xs while other blocks still read their ebuf regions)
    int* blkhistT    = (int*)d_ws;                         // 512*nblk
    int* buckettotal = blkhistT + 512 * nblk;              // 512
    int* bucketbase  = buckettotal + 512;                  // 513 (+pad to 516)
    int* srcs        = bucketbase + 516;                   // E + NB*4*NPB
    int* begs        = srcs + E + NB * 4 * NPB;            // n
    int* lens        = begs + n;                           // n
    float* dinv      = (float*)(lens + n);                 // n
    size_t xsoff     = (size_t)(((int*)dinv + n) - (int*)d_ws);
    xsoff            = (xsoff + 31) & ~(size_t)31;         // 128B-align for uint4
    unsigned* xs     = (unsigned*)d_ws + xsoff;            // (n+1)*32
    unsigned* ebuf   = xs + (size_t)(n + 1) * 32;          // E

    float* out = (float*)d_out;

    int aggblocks = 2048;                  // 8 blocks/CU (LDS-limited residency)
    if (aggblocks > nquads) aggblocks = nquads;

    histA_kernel <<<nblk, 256, 0, stream>>>(ei, blkhistT, E, nblk);
    scanB1_kernel<<<512, 256, 0, stream>>>(blkhistT, buckettotal, nblk);
    scanB2_kernel<<<1, 512, 0, stream>>>(buckettotal, bucketbase);
    partC_kernel <<<nblk, 256, 0, stream>>>(ei, blkhistT, bucketbase, ebuf, E, nblk);
    csrD_kernel  <<<NB, 256, 0, stream>>>(ebuf, bucketbase, x, srcs, begs, lens, dinv, xs, n);
    agg_kernel   <<<aggblocks, 256, 0, stream>>>(begs, lens, srcs, dinv,
                                                 (const uint4*)xs, W, b, out, n, nquads);
}